// Round 9
// baseline (242.072 us; speedup 1.0000x reference)
//
#include <hip/hip_runtime.h>

typedef float v2f __attribute__((ext_vector_type(2)));

#define HH 192
#define WW 192
#define BATCH 16
#define PLANE (HH*WW)              /* 36864 */
#define NELEM (BATCH*2*PLANE)      /* 1179648 */

// Tile: 96 px wide x 8 rows, 384 threads (6 waves), 2 px per thread.
// Grid = (2,24,16) = 768 blocks = 3 blocks/CU -> 18 waves/CU (4.5/SIMD),
// 1.5x R5's occupancy at IDENTICAL tile/block-count (clean occupancy A/B).
#define TILEX 96
#define TILEY 8
#define SW 100  /* TILEX + 4 */
#define SH2 12  /* TILEY + 4 */
#define NPAIR 600   /* 12 rows x 50 site-pairs; both channels per site */

// Workspace: [0..200) K8T conv weights (tap-major [25][8]);
// [256..414) PP packed poly weight PAIRS as v2f {k=0, k=1};
// bufA at ws+512, bufH after.
//
// PP index map (v2f units):
//  0..11  W0a[i]={pw0[i],pw0[24+i]}      12..23 W0b[i]={pw0[12+i],pw0[36+i]}
//  24 B0a={pb0[0],pb0[2]}  25 B0b={pb0[1],pb0[3]}
//  26..37 W1a[i]={pw1[i],pw1[26+i]}      38..49 W1b[i]={pw1[13+i],pw1[39+i]}
//  50 W112={pw1[12],pw1[38]}  51 W125={pw1[25],pw1[51]}
//  52 B1a={pb1[0],pb1[2]}  53 B1b={pb1[1],pb1[3]}
//  54..67 WF[i]={pwf[i],pwf[14+i]}  (66=WF12, 67=WF13)
//  68 BF={pbf[0],pbf[1]}
//  69,70 GW0a; 71,72 GW0b; 73,74 GW1a; 75,76 GW1b; 77,78 GWF
__global__ void prep_kernel(const float* __restrict__ kern,
                            const float* __restrict__ pw0, const float* __restrict__ pb0,
                            const float* __restrict__ pw1, const float* __restrict__ pb1,
                            const float* __restrict__ pwf, const float* __restrict__ pbf,
                            float* __restrict__ ws)
{
    int t = blockIdx.x * blockDim.x + threadIdx.x;
    if (t < 200) {
        const float inv  = 1.0f / 0.0327249f;
        const float inv2 = inv * inv;
        const float sc[6] = {1.0f, inv, inv, inv2, inv2, inv2};
        int o = t / 8, j = t % 8, dy = o / 5, dx = o % 5;
        float v;
        if (j < 6)       v =  kern[j*25 + dy*5 + dx] * sc[j];
        else if (j == 6) v = -kern[1*25 + dy*5 + (4-dx)] * sc[1];
        else             v = -kern[2*25 + (4-dy)*5 + dx] * sc[2];
        ws[o*8 + j] = v;
    } else if (t < 279) {
        int p = t - 200;
        int arr, a, b;
        if (p < 12)       { arr=0; a=p;      b=24+p; }
        else if (p < 24)  { int i=p-12; arr=0; a=12+i; b=36+i; }
        else if (p == 24) { arr=1; a=0; b=2; }
        else if (p == 25) { arr=1; a=1; b=3; }
        else if (p < 38)  { int i=p-26; arr=2; a=i;    b=26+i; }
        else if (p < 50)  { int i=p-38; arr=2; a=13+i; b=39+i; }
        else if (p == 50) { arr=2; a=12; b=38; }
        else if (p == 51) { arr=2; a=25; b=51; }
        else if (p == 52) { arr=3; a=0; b=2; }
        else if (p == 53) { arr=3; a=1; b=3; }
        else if (p < 68)  { int i=p-54; arr=4; a=i; b=14+i; }
        else if (p == 68) { arr=5; a=0; b=1; }
        else {
            const signed char   A0[10] = {1,2,13,14,1,2,14,15,1,2};
            const signed char   A1[10] = {31,32,43,44,33,34,46,47,21,22};
            const unsigned char AR[10] = {0,0,0,0,2,2,2,2,4,4};
            int i = p - 69; arr = AR[i]; a = A0[i]; b = A1[i];
        }
        const float* bases[6] = {pw0, pb0, pw1, pb1, pwf, pbf};
        v2f v; v[0] = bases[arr][a]; v[1] = bases[arr][b];
        ((v2f*)(ws + 256))[p] = v;
    }
}

// One RHS eval fused with axpy: uout = ubase + alpha * rhs(uin).
// PACKED-FP32 (v_pk_fma_f32): conv packs the 2 input channels; poly packs the
// 2 output heads k. Per-pixel arithmetic identical to the verified R5 kernel
// (bit-exact). Staging uses float2-pair loads + ds_write_b128 (pair-aligned
// wrap safe: gx0 and WW both even). When ubase==uin the base values are read
// from the staged LDS center (bit-exact, skips the global round trip).
__global__ __launch_bounds__(384, 4) void rhs_kernel(
    const float* __restrict__ uin,
    const float* __restrict__ ubase,
    float* __restrict__ uout,
    const float* __restrict__ ws,
    float alpha)
{
    const float* K8T = ws;
    const v2f* PP = (const v2f*)(ws + 256);

    __shared__ v2f sh[SH2][SW];
    const int b   = blockIdx.z;
    const int ty0 = blockIdx.y * TILEY;
    const int tx0 = blockIdx.x * TILEX;
    const int tid = threadIdx.x;
    const size_t bo = (size_t)b * 2 * PLANE;

    // ---- Staging: 600 site-pairs, <=2 iters/thread. One float2 per channel,
    // one 16B LDS write per pair.
    const float* uin_b = uin + bo;
    for (int i = tid; i < NPAIR; i += 384) {
        const int ly  = i / 50;
        const int cp  = i - ly * 50;
        const int col = cp * 2;
        int gy = ty0 + ly - 2;  if (gy < 0) gy += HH; else if (gy >= HH) gy -= HH;
        int gx0 = tx0 + col - 2; if (gx0 < 0) gx0 += WW; else if (gx0 >= WW) gx0 -= WW;
        const int gi = gy*WW + gx0;
        const float2 a = *(const float2*)(uin_b + gi);
        const float2 c = *(const float2*)(uin_b + PLANE + gi);
        float4 st; st.x = a.x; st.y = c.x; st.z = a.y; st.w = c.y;
        *(float4*)&sh[ly][col] = st;
    }
    __syncthreads();

    const int cy = tid / 48;            // 0..7
    const int x2 = (tid - cy * 48) * 2; // 0,2,..,94

    // ---- Conv: D2[px][j] = v2f over channels. dy loop rolled (code size).
    v2f D2[2][8];
    #pragma unroll
    for (int p = 0; p < 2; ++p)
        #pragma unroll
        for (int j = 0; j < 8; ++j)
            D2[p][j] = (v2f){0.0f, 0.0f};

    #pragma unroll 1
    for (int dy = 0; dy < 5; ++dy) {
        v2f row[6];
        #pragma unroll
        for (int dx = 0; dx < 6; ++dx)
            row[dx] = sh[cy + dy][x2 + dx];
        const float* Kt = K8T + dy * 40;   // 5 taps x 8 weights
        #pragma unroll
        for (int dx = 0; dx < 5; ++dx) {
            #pragma unroll
            for (int j = 0; j < 8; ++j) {
                const float w = Kt[dx*8 + j];
                D2[0][j] += row[dx]   * w;   // v_pk_fma_f32: both channels
                D2[1][j] += row[dx+1] * w;
            }
        }
    }

    // Feature i of pixel p: channel = i/6, map = i%6.
#define Z(p,i) (D2[p][(i)%6][(i)/6])

    v2f res[2];   // {k=0, k=1} per pixel
    #pragma unroll
    for (int p = 0; p < 2; ++p) {
        // ---- Base pass, packed over k (base features identical for both k).
        v2f o0 = PP[24], o1 = PP[25];
        #pragma unroll
        for (int i = 0; i < 12; ++i) {
            const float zv = Z(p, i);
            o0 += PP[i]    * zv;
            o1 += PP[12+i] * zv;
        }
        const v2f pb = o0 * o1;
        v2f q0 = PP[52] + PP[50]*pb;
        v2f q1 = PP[53] + PP[51]*pb;
        #pragma unroll
        for (int i = 0; i < 12; ++i) {
            const float zv = Z(p, i);
            q0 += PP[26+i] * zv;
            q1 += PP[38+i] * zv;
        }

        // ---- Gradients at the two upwind-selectable features, packed over k.
        const v2f t1 = o1*PP[69] + o0*PP[71];
        const v2f g1 = PP[77] + PP[66]*t1
            + PP[67]*(q1*(PP[73] + PP[50]*t1) + q0*(PP[75] + PP[51]*t1));
        const v2f t2 = o1*PP[70] + o0*PP[72];
        const v2f g2 = PP[78] + PP[66]*t2
            + PP[67]*(q1*(PP[74] + PP[50]*t2) + q0*(PP[76] + PP[51]*t2));

        // Selections (shared feature vector: all 4 replacements visible to both k).
        const float s1 = (g1[0] > 0.0f) ? Z(p,1) : D2[p][6][0];
        const float s2 = (g2[0] > 0.0f) ? Z(p,2) : D2[p][7][0];
        const float s3 = (g1[1] > 0.0f) ? Z(p,7) : D2[p][6][1];
        const float s4 = (g2[1] > 0.0f) ? Z(p,8) : D2[p][7][1];
#define XV(i) ((i)==1 ? s1 : (i)==2 ? s2 : (i)==7 ? s3 : (i)==8 ? s4 : Z(p,(i)))

        // ---- Forward poly at selected features, packed over k.
        v2f f0 = PP[24], f1 = PP[25];
        #pragma unroll
        for (int i = 0; i < 12; ++i) {
            const float xv = XV(i);
            f0 += PP[i]    * xv;
            f1 += PP[12+i] * xv;
        }
        const v2f pf = f0 * f1;
        v2f r0 = PP[52] + PP[50]*pf;
        v2f r1 = PP[53] + PP[51]*pf;
        v2f y  = PP[68] + PP[66]*pf;
        #pragma unroll
        for (int i = 0; i < 12; ++i) {
            const float xv = XV(i);
            r0 += PP[26+i] * xv;
            r1 += PP[38+i] * xv;
            y  += PP[54+i] * xv;
        }
        res[p] = y + PP[67]*(r0*r1);
#undef XV
    }

    // ---- Base + write. When ubase==uin, base = staged center (bit-exact).
    const int oy = ty0 + cy, ox = tx0 + x2;
    const size_t o0i = bo + (size_t)oy * WW + ox;
    float2 base0, base1;
    if (ubase == uin) {
        const v2f c0 = sh[cy+2][x2+2];
        const v2f c1 = sh[cy+2][x2+3];
        base0.x = c0[0]; base0.y = c1[0];
        base1.x = c0[1]; base1.y = c1[1];
    } else {
        base0 = *(const float2*)(ubase + o0i);
        base1 = *(const float2*)(ubase + o0i + PLANE);
    }
    float2 r0, r1;
    r0.x = base0.x + alpha * res[0][0];
    r0.y = base0.y + alpha * res[1][0];
    r1.x = base1.x + alpha * res[0][1];
    r1.y = base1.y + alpha * res[1][1];
    *(float2*)(uout + o0i)         = r0;
    *(float2*)(uout + o0i + PLANE) = r1;
}

extern "C" void kernel_launch(void* const* d_in, const int* in_sizes, int n_in,
                              void* d_out, int out_size, void* d_ws, size_t ws_size,
                              hipStream_t stream)
{
    const float* init = (const float*)d_in[0];
    const float* kern = (const float*)d_in[1];
    const float* pw0  = (const float*)d_in[2];
    const float* pb0  = (const float*)d_in[3];
    const float* pw1  = (const float*)d_in[4];
    const float* pb1  = (const float*)d_in[5];
    const float* pwf  = (const float*)d_in[6];
    const float* pbf  = (const float*)d_in[7];
    float* out = (float*)d_out;
    float* ws  = (float*)d_ws;

    float* bufA = ws + 512;            // NELEM floats: u_n
    float* bufH = bufA + NELEM;        // NELEM floats: u_half

    prep_kernel<<<dim3(1), dim3(320), 0, stream>>>(kern, pw0, pb0, pw1, pb1, pwf, pbf, ws);

    const dim3 grid(WW/TILEX, HH/TILEY, BATCH);   // (2, 24, 16) = 768 blocks
    const dim3 block(384);
    const float DTF = 0.2f, DTH = 0.1f;

    // T=1 -> 5 RK2 (midpoint) steps, 2 RHS evals each (sequential dependency).
    rhs_kernel<<<grid, block, 0, stream>>>(init, init, bufH, ws, DTH);
    rhs_kernel<<<grid, block, 0, stream>>>(bufH, init, bufA, ws, DTF);
    for (int s = 0; s < 3; ++s) {
        rhs_kernel<<<grid, block, 0, stream>>>(bufA, bufA, bufH, ws, DTH);
        rhs_kernel<<<grid, block, 0, stream>>>(bufH, bufA, bufA, ws, DTF);
    }
    rhs_kernel<<<grid, block, 0, stream>>>(bufA, bufA, bufH, ws, DTH);
    rhs_kernel<<<grid, block, 0, stream>>>(bufH, bufA, out,  ws, DTF);
}

// Round 10
// 198.074 us; speedup vs baseline: 1.2221x; 1.2221x over previous
//
#include <hip/hip_runtime.h>

typedef float v2f __attribute__((ext_vector_type(2)));

#define HH 192
#define WW 192
#define BATCH 16
#define PLANE (HH*WW)              /* 36864 */
#define NELEM (BATCH*2*PLANE)      /* 1179648 */

// Tile: 96 px wide x 8 rows, 256 threads, 3 px per thread. Halo 2 each side.
// Grid = (2,24,16) = 768 blocks = 3 blocks/CU, 12 waves/CU -- the measured
// sharp optimum (R5). R7 (more blocks), R8 (fusion), R9 (6 waves) all lost.
#define TILEX 96
#define TILEY 8
#define SW 100  /* TILEX + 4 */
#define SH2 12  /* TILEY + 4 */
#define NPAIR 600   /* 12 rows x 50 site-pairs; both channels per site */

// Workspace: [0..200) K8T conv weights (tap-major [25][8]);
// [256..414) PP packed poly weight PAIRS as v2f {k=0, k=1};
// bufA at ws+512, bufH after.
//
// PP index map (v2f units):
//  0..11  W0a[i]={pw0[i],pw0[24+i]}      12..23 W0b[i]={pw0[12+i],pw0[36+i]}
//  24 B0a={pb0[0],pb0[2]}  25 B0b={pb0[1],pb0[3]}
//  26..37 W1a[i]={pw1[i],pw1[26+i]}      38..49 W1b[i]={pw1[13+i],pw1[39+i]}
//  50 W112={pw1[12],pw1[38]}  51 W125={pw1[25],pw1[51]}
//  52 B1a={pb1[0],pb1[2]}  53 B1b={pb1[1],pb1[3]}
//  54..67 WF[i]={pwf[i],pwf[14+i]}  (66=WF12, 67=WF13)
//  68 BF={pbf[0],pbf[1]}
//  69,70 GW0a; 71,72 GW0b; 73,74 GW1a; 75,76 GW1b; 77,78 GWF
__global__ void prep_kernel(const float* __restrict__ kern,
                            const float* __restrict__ pw0, const float* __restrict__ pb0,
                            const float* __restrict__ pw1, const float* __restrict__ pb1,
                            const float* __restrict__ pwf, const float* __restrict__ pbf,
                            float* __restrict__ ws)
{
    int t = blockIdx.x * blockDim.x + threadIdx.x;
    if (t < 200) {
        const float inv  = 1.0f / 0.0327249f;
        const float inv2 = inv * inv;
        const float sc[6] = {1.0f, inv, inv, inv2, inv2, inv2};
        int o = t / 8, j = t % 8, dy = o / 5, dx = o % 5;
        float v;
        if (j < 6)       v =  kern[j*25 + dy*5 + dx] * sc[j];
        else if (j == 6) v = -kern[1*25 + dy*5 + (4-dx)] * sc[1];
        else             v = -kern[2*25 + (4-dy)*5 + dx] * sc[2];
        ws[o*8 + j] = v;
    } else if (t < 279) {
        int p = t - 200;
        int arr, a, b;
        if (p < 12)       { arr=0; a=p;      b=24+p; }
        else if (p < 24)  { int i=p-12; arr=0; a=12+i; b=36+i; }
        else if (p == 24) { arr=1; a=0; b=2; }
        else if (p == 25) { arr=1; a=1; b=3; }
        else if (p < 38)  { int i=p-26; arr=2; a=i;    b=26+i; }
        else if (p < 50)  { int i=p-38; arr=2; a=13+i; b=39+i; }
        else if (p == 50) { arr=2; a=12; b=38; }
        else if (p == 51) { arr=2; a=25; b=51; }
        else if (p == 52) { arr=3; a=0; b=2; }
        else if (p == 53) { arr=3; a=1; b=3; }
        else if (p < 68)  { int i=p-54; arr=4; a=i; b=14+i; }
        else if (p == 68) { arr=5; a=0; b=1; }
        else {
            const signed char   A0[10] = {1,2,13,14,1,2,14,15,1,2};
            const signed char   A1[10] = {31,32,43,44,33,34,46,47,21,22};
            const unsigned char AR[10] = {0,0,0,0,2,2,2,2,4,4};
            int i = p - 69; arr = AR[i]; a = A0[i]; b = A1[i];
        }
        const float* bases[6] = {pw0, pb0, pw1, pb1, pwf, pbf};
        v2f v; v[0] = bases[arr][a]; v[1] = bases[arr][b];
        ((v2f*)(ws + 256))[p] = v;
    }
}

// One RHS eval fused with axpy: uout = ubase + alpha * rhs(uin).
// PACKED-FP32 (v_pk_fma_f32): conv packs the 2 input channels; poly packs the
// 2 output heads k. DELTA-FORWARD poly: the upwind-selected feature vector
// differs from the base vector in <=4 scalar entries (d1..d4, 0 when grad>0),
// so the forward pass = base pass + rank-4 correction (exact algebra).
// Staging: float2-pair loads + one 16B LDS write per site-pair (wrap-safe:
// gx0 and WW both even). When ubase==uin, base = staged LDS center.
__global__ __launch_bounds__(256, 3) void rhs_kernel(
    const float* __restrict__ uin,
    const float* __restrict__ ubase,
    float* __restrict__ uout,
    const float* __restrict__ ws,
    float alpha)
{
    const float* K8T = ws;
    const v2f* PP = (const v2f*)(ws + 256);

    __shared__ v2f sh[SH2][SW];
    const int b   = blockIdx.z;
    const int ty0 = blockIdx.y * TILEY;
    const int tx0 = blockIdx.x * TILEX;
    const int tid = threadIdx.x;
    const size_t bo = (size_t)b * 2 * PLANE;

    // ---- Staging: 600 site-pairs, 2-3 iters/thread. One float2 per channel,
    // one 16B LDS write per pair.
    const float* uin_b = uin + bo;
    for (int i = tid; i < NPAIR; i += 256) {
        const int ly  = i / 50;
        const int cp  = i - ly * 50;
        const int col = cp * 2;
        int gy = ty0 + ly - 2;  if (gy < 0) gy += HH; else if (gy >= HH) gy -= HH;
        int gx0 = tx0 + col - 2; if (gx0 < 0) gx0 += WW; else if (gx0 >= WW) gx0 -= WW;
        const int gi = gy*WW + gx0;
        const float2 a = *(const float2*)(uin_b + gi);
        const float2 c = *(const float2*)(uin_b + PLANE + gi);
        float4 st; st.x = a.x; st.y = c.x; st.z = a.y; st.w = c.y;
        *(float4*)&sh[ly][col] = st;
    }
    __syncthreads();

    const int cy = tid >> 5;            // 0..7
    const int x3 = (tid & 31) * 3;      // 0,3,..,93

    // ---- Conv: D2[px][j] = v2f over channels. dy loop rolled (code size).
    v2f D2[3][8];
    #pragma unroll
    for (int p = 0; p < 3; ++p)
        #pragma unroll
        for (int j = 0; j < 8; ++j)
            D2[p][j] = (v2f){0.0f, 0.0f};

    #pragma unroll 1
    for (int dy = 0; dy < 5; ++dy) {
        v2f row[7];
        #pragma unroll
        for (int dx = 0; dx < 7; ++dx)
            row[dx] = sh[cy + dy][x3 + dx];
        const float* Kt = K8T + dy * 40;   // 5 taps x 8 weights
        #pragma unroll
        for (int dx = 0; dx < 5; ++dx) {
            #pragma unroll
            for (int j = 0; j < 8; ++j) {
                const float w = Kt[dx*8 + j];
                D2[0][j] += row[dx]   * w;   // v_pk_fma_f32: both channels
                D2[1][j] += row[dx+1] * w;
                D2[2][j] += row[dx+2] * w;
            }
        }
    }

    // Feature i of pixel p: channel = i/6, map = i%6.
#define Z(p,i) (D2[p][(i)%6][(i)/6])

    v2f res[3];   // {k=0, k=1} per pixel
    #pragma unroll
    for (int p = 0; p < 3; ++p) {
        // ---- Base pass, packed over k (base features identical for both k).
        // Also accumulates yb = final-layer linear part at base features.
        v2f o0 = PP[24], o1 = PP[25];
        #pragma unroll
        for (int i = 0; i < 12; ++i) {
            const float zv = Z(p, i);
            o0 += PP[i]    * zv;
            o1 += PP[12+i] * zv;
        }
        const v2f pb = o0 * o1;
        v2f q0 = PP[52] + PP[50]*pb;
        v2f q1 = PP[53] + PP[51]*pb;
        v2f yb = PP[68] + PP[66]*pb;
        #pragma unroll
        for (int i = 0; i < 12; ++i) {
            const float zv = Z(p, i);
            q0 += PP[26+i] * zv;
            q1 += PP[38+i] * zv;
            yb += PP[54+i] * zv;
        }

        // ---- Gradients at the two upwind-selectable features, packed over k.
        const v2f t1 = o1*PP[69] + o0*PP[71];
        const v2f g1 = PP[77] + PP[66]*t1
            + PP[67]*(q1*(PP[73] + PP[50]*t1) + q0*(PP[75] + PP[51]*t1));
        const v2f t2 = o1*PP[70] + o0*PP[72];
        const v2f g2 = PP[78] + PP[66]*t2
            + PP[67]*(q1*(PP[74] + PP[50]*t2) + q0*(PP[76] + PP[51]*t2));

        // ---- Selection deltas (scalars; shared feature vector for both k).
        const float d1 = (g1[0] > 0.0f) ? 0.0f : (D2[p][6][0] - Z(p,1));
        const float d2 = (g2[0] > 0.0f) ? 0.0f : (D2[p][7][0] - Z(p,2));
        const float d3 = (g1[1] > 0.0f) ? 0.0f : (D2[p][6][1] - Z(p,7));
        const float d4 = (g2[1] > 0.0f) ? 0.0f : (D2[p][7][1] - Z(p,8));

        // ---- Delta-forward: base + rank-4 correction (exact algebra).
        v2f f0 = o0 + PP[1]*d1;  f0 += PP[2]*d2;  f0 += PP[7]*d3;  f0 += PP[8]*d4;
        v2f f1 = o1 + PP[13]*d1; f1 += PP[14]*d2; f1 += PP[19]*d3; f1 += PP[20]*d4;
        const v2f pf = f0 * f1;
        const v2f dp = pf - pb;
        v2f r0 = q0 + PP[27]*d1; r0 += PP[28]*d2; r0 += PP[33]*d3; r0 += PP[34]*d4;
        r0 += PP[50]*dp;
        v2f r1 = q1 + PP[39]*d1; r1 += PP[40]*d2; r1 += PP[45]*d3; r1 += PP[46]*d4;
        r1 += PP[51]*dp;
        v2f y  = yb + PP[55]*d1; y  += PP[56]*d2; y  += PP[61]*d3; y  += PP[62]*d4;
        y  += PP[66]*dp;
        res[p] = y + PP[67]*(r0*r1);
    }

    // ---- Base + write. When ubase==uin, base = staged center (bit-exact).
    const int oy = ty0 + cy, ox = tx0 + x3;
    const size_t o0i = bo + (size_t)oy * WW + ox;
    float bb0[3], bb1[3];
    if (ubase == uin) {
        #pragma unroll
        for (int p = 0; p < 3; ++p) {
            const v2f c = sh[cy+2][x3+2+p];
            bb0[p] = c[0]; bb1[p] = c[1];
        }
    } else {
        #pragma unroll
        for (int p = 0; p < 3; ++p) {
            bb0[p] = ubase[o0i + p];
            bb1[p] = ubase[o0i + PLANE + p];
        }
    }
    #pragma unroll
    for (int p = 0; p < 3; ++p) {
        uout[o0i + p]         = bb0[p] + alpha * res[p][0];
        uout[o0i + PLANE + p] = bb1[p] + alpha * res[p][1];
    }
}

extern "C" void kernel_launch(void* const* d_in, const int* in_sizes, int n_in,
                              void* d_out, int out_size, void* d_ws, size_t ws_size,
                              hipStream_t stream)
{
    const float* init = (const float*)d_in[0];
    const float* kern = (const float*)d_in[1];
    const float* pw0  = (const float*)d_in[2];
    const float* pb0  = (const float*)d_in[3];
    const float* pw1  = (const float*)d_in[4];
    const float* pb1  = (const float*)d_in[5];
    const float* pwf  = (const float*)d_in[6];
    const float* pbf  = (const float*)d_in[7];
    float* out = (float*)d_out;
    float* ws  = (float*)d_ws;

    float* bufA = ws + 512;            // NELEM floats: u_n
    float* bufH = bufA + NELEM;        // NELEM floats: u_half

    prep_kernel<<<dim3(1), dim3(320), 0, stream>>>(kern, pw0, pb0, pw1, pb1, pwf, pbf, ws);

    const dim3 grid(WW/TILEX, HH/TILEY, BATCH);   // (2, 24, 16) = 768 blocks
    const dim3 block(256);
    const float DTF = 0.2f, DTH = 0.1f;

    // T=1 -> 5 RK2 (midpoint) steps, 2 RHS evals each (sequential dependency).
    rhs_kernel<<<grid, block, 0, stream>>>(init, init, bufH, ws, DTH);
    rhs_kernel<<<grid, block, 0, stream>>>(bufH, init, bufA, ws, DTF);
    for (int s = 0; s < 3; ++s) {
        rhs_kernel<<<grid, block, 0, stream>>>(bufA, bufA, bufH, ws, DTH);
        rhs_kernel<<<grid, block, 0, stream>>>(bufH, bufA, bufA, ws, DTF);
    }
    rhs_kernel<<<grid, block, 0, stream>>>(bufA, bufA, bufH, ws, DTH);
    rhs_kernel<<<grid, block, 0, stream>>>(bufH, bufA, out,  ws, DTF);
}

// Round 11
// 189.103 us; speedup vs baseline: 1.2801x; 1.0474x over previous
//
#include <hip/hip_runtime.h>

typedef float v2f __attribute__((ext_vector_type(2)));

#define HH 192
#define WW 192
#define BATCH 16
#define PLANE (HH*WW)              /* 36864 */
#define NELEM (BATCH*2*PLANE)      /* 1179648 */

// Tile: 96 px wide x 8 rows, 256 threads, 3 px per thread. Halo 2 each side.
// Grid = (2,24,16) = 768 blocks = 3 blocks/CU, 12 waves/CU -- the measured
// sharp optimum (R5). R7 (more blocks), R8 (fusion), R9 (6 waves) all lost.
#define TILEX 96
#define TILEY 8
#define SW 100  /* TILEX + 4 */
#define SH2 12  /* TILEY + 4 */
#define NPAIR 600   /* 12 rows x 50 site-pairs; both channels per site */

// Mode bits (wave-uniform): 1 = uin planar (init); 2 = base from staged LDS
// center (ubase==uin); 4 = base planar (init); 8 = uout planar (final out).
// Otherwise the pointer is a channel-interleaved v2f[site] buffer.
#define M_INP  1
#define M_BLDS 2
#define M_BPLN 4
#define M_OUTP 8

// Workspace: [0..200) K8T conv weights (tap-major [25][8]);
// [256..414) PP packed poly weight PAIRS as v2f {k=0, k=1};
// bufA at ws+512, bufH after (both stored channel-INTERLEAVED v2f[site]).
//
// PP index map (v2f units):
//  0..11  W0a[i]={pw0[i],pw0[24+i]}      12..23 W0b[i]={pw0[12+i],pw0[36+i]}
//  24 B0a={pb0[0],pb0[2]}  25 B0b={pb0[1],pb0[3]}
//  26..37 W1a[i]={pw1[i],pw1[26+i]}      38..49 W1b[i]={pw1[13+i],pw1[39+i]}
//  50 W112={pw1[12],pw1[38]}  51 W125={pw1[25],pw1[51]}
//  52 B1a={pb1[0],pb1[2]}  53 B1b={pb1[1],pb1[3]}
//  54..67 WF[i]={pwf[i],pwf[14+i]}  (66=WF12, 67=WF13)
//  68 BF={pbf[0],pbf[1]}
//  69,70 GW0a; 71,72 GW0b; 73,74 GW1a; 75,76 GW1b; 77,78 GWF
__global__ void prep_kernel(const float* __restrict__ kern,
                            const float* __restrict__ pw0, const float* __restrict__ pb0,
                            const float* __restrict__ pw1, const float* __restrict__ pb1,
                            const float* __restrict__ pwf, const float* __restrict__ pbf,
                            float* __restrict__ ws)
{
    int t = blockIdx.x * blockDim.x + threadIdx.x;
    if (t < 200) {
        const float inv  = 1.0f / 0.0327249f;
        const float inv2 = inv * inv;
        const float sc[6] = {1.0f, inv, inv, inv2, inv2, inv2};
        int o = t / 8, j = t % 8, dy = o / 5, dx = o % 5;
        float v;
        if (j < 6)       v =  kern[j*25 + dy*5 + dx] * sc[j];
        else if (j == 6) v = -kern[1*25 + dy*5 + (4-dx)] * sc[1];
        else             v = -kern[2*25 + (4-dy)*5 + dx] * sc[2];
        ws[o*8 + j] = v;
    } else if (t < 279) {
        int p = t - 200;
        int arr, a, b;
        if (p < 12)       { arr=0; a=p;      b=24+p; }
        else if (p < 24)  { int i=p-12; arr=0; a=12+i; b=36+i; }
        else if (p == 24) { arr=1; a=0; b=2; }
        else if (p == 25) { arr=1; a=1; b=3; }
        else if (p < 38)  { int i=p-26; arr=2; a=i;    b=26+i; }
        else if (p < 50)  { int i=p-38; arr=2; a=13+i; b=39+i; }
        else if (p == 50) { arr=2; a=12; b=38; }
        else if (p == 51) { arr=2; a=25; b=51; }
        else if (p == 52) { arr=3; a=0; b=2; }
        else if (p == 53) { arr=3; a=1; b=3; }
        else if (p < 68)  { int i=p-54; arr=4; a=i; b=14+i; }
        else if (p == 68) { arr=5; a=0; b=1; }
        else {
            const signed char   A0[10] = {1,2,13,14,1,2,14,15,1,2};
            const signed char   A1[10] = {31,32,43,44,33,34,46,47,21,22};
            const unsigned char AR[10] = {0,0,0,0,2,2,2,2,4,4};
            int i = p - 69; arr = AR[i]; a = A0[i]; b = A1[i];
        }
        const float* bases[6] = {pw0, pb0, pw1, pb1, pwf, pbf};
        v2f v; v[0] = bases[arr][a]; v[1] = bases[arr][b];
        ((v2f*)(ws + 256))[p] = v;
    }
}

// One RHS eval fused with axpy: uout = ubase + alpha * rhs(uin).
// PACKED-FP32 (v_pk_fma_f32) + DELTA-FORWARD poly (verified R10, bit-exact
// algebra). This round: channel-interleaved intermediate buffers (one float4
// staging load per site-pair, b64 base/stores) + base loads issued BEFORE the
// staging barrier (latency hidden under the barrier wait). Arithmetic and
// rounding identical to R10.
__global__ __launch_bounds__(256, 3) void rhs_kernel(
    const float* __restrict__ uin,
    const float* __restrict__ ubase,
    float* __restrict__ uout,
    const float* __restrict__ ws,
    float alpha, int mode)
{
    const float* K8T = ws;
    const v2f* PP = (const v2f*)(ws + 256);

    __shared__ v2f sh[SH2][SW];
    const int b   = blockIdx.z;
    const int ty0 = blockIdx.y * TILEY;
    const int tx0 = blockIdx.x * TILEX;
    const int tid = threadIdx.x;
    const size_t bo = (size_t)b * 2 * PLANE;

    // ---- Staging: 600 site-pairs, 2-3 iters/thread.
    if (mode & M_INP) {
        // planar init: two float2 loads -> one 16B LDS write per pair
        const float* uin_b = uin + bo;
        for (int i = tid; i < NPAIR; i += 256) {
            const int ly  = i / 50;
            const int cp  = i - ly * 50;
            const int col = cp * 2;
            int gy = ty0 + ly - 2;  if (gy < 0) gy += HH; else if (gy >= HH) gy -= HH;
            int gx0 = tx0 + col - 2; if (gx0 < 0) gx0 += WW; else if (gx0 >= WW) gx0 -= WW;
            const int gi = gy*WW + gx0;
            const float2 a = *(const float2*)(uin_b + gi);
            const float2 c = *(const float2*)(uin_b + PLANE + gi);
            float4 st; st.x = a.x; st.y = c.x; st.z = a.y; st.w = c.y;
            *(float4*)&sh[ly][col] = st;
        }
    } else {
        // interleaved buffer: ONE float4 load per pair (16B/lane, coalesced)
        const v2f* uin_i = (const v2f*)uin + (size_t)b * PLANE;
        for (int i = tid; i < NPAIR; i += 256) {
            const int ly  = i / 50;
            const int cp  = i - ly * 50;
            const int col = cp * 2;
            int gy = ty0 + ly - 2;  if (gy < 0) gy += HH; else if (gy >= HH) gy -= HH;
            int gx0 = tx0 + col - 2; if (gx0 < 0) gx0 += WW; else if (gx0 >= WW) gx0 -= WW;
            *(float4*)&sh[ly][col] = *(const float4*)(uin_i + gy*WW + gx0);
        }
    }

    const int cy = tid >> 5;            // 0..7
    const int x3 = (tid & 31) * 3;      // 0,3,..,93
    const int oy = ty0 + cy, ox = tx0 + x3;
    const size_t o0i = bo + (size_t)oy * WW + ox;              // planar index
    const size_t si  = (size_t)b * PLANE + (size_t)oy * WW + ox; // site index

    // ---- Base loads issued EARLY (before barrier) when from global.
    float bb0[3], bb1[3];
    if (!(mode & M_BLDS)) {
        if (mode & M_BPLN) {
            #pragma unroll
            for (int p = 0; p < 3; ++p) {
                bb0[p] = ubase[o0i + p];
                bb1[p] = ubase[o0i + PLANE + p];
            }
        } else {
            const v2f* ub = (const v2f*)ubase;
            #pragma unroll
            for (int p = 0; p < 3; ++p) {
                const v2f c = ub[si + p];
                bb0[p] = c[0]; bb1[p] = c[1];
            }
        }
    }
    __syncthreads();
    if (mode & M_BLDS) {
        #pragma unroll
        for (int p = 0; p < 3; ++p) {
            const v2f c = sh[cy+2][x3+2+p];
            bb0[p] = c[0]; bb1[p] = c[1];
        }
    }

    // ---- Conv: D2[px][j] = v2f over channels. dy loop rolled (code size).
    v2f D2[3][8];
    #pragma unroll
    for (int p = 0; p < 3; ++p)
        #pragma unroll
        for (int j = 0; j < 8; ++j)
            D2[p][j] = (v2f){0.0f, 0.0f};

    #pragma unroll 1
    for (int dy = 0; dy < 5; ++dy) {
        v2f row[7];
        #pragma unroll
        for (int dx = 0; dx < 7; ++dx)
            row[dx] = sh[cy + dy][x3 + dx];
        const float* Kt = K8T + dy * 40;   // 5 taps x 8 weights
        #pragma unroll
        for (int dx = 0; dx < 5; ++dx) {
            #pragma unroll
            for (int j = 0; j < 8; ++j) {
                const float w = Kt[dx*8 + j];
                D2[0][j] += row[dx]   * w;   // v_pk_fma_f32: both channels
                D2[1][j] += row[dx+1] * w;
                D2[2][j] += row[dx+2] * w;
            }
        }
    }

    // Feature i of pixel p: channel = i/6, map = i%6.
#define Z(p,i) (D2[p][(i)%6][(i)/6])

    v2f res[3];   // {k=0, k=1} per pixel
    #pragma unroll
    for (int p = 0; p < 3; ++p) {
        // ---- Base pass, packed over k; also accumulates yb (final linear).
        v2f o0 = PP[24], o1 = PP[25];
        #pragma unroll
        for (int i = 0; i < 12; ++i) {
            const float zv = Z(p, i);
            o0 += PP[i]    * zv;
            o1 += PP[12+i] * zv;
        }
        const v2f pb = o0 * o1;
        v2f q0 = PP[52] + PP[50]*pb;
        v2f q1 = PP[53] + PP[51]*pb;
        v2f yb = PP[68] + PP[66]*pb;
        #pragma unroll
        for (int i = 0; i < 12; ++i) {
            const float zv = Z(p, i);
            q0 += PP[26+i] * zv;
            q1 += PP[38+i] * zv;
            yb += PP[54+i] * zv;
        }

        // ---- Gradients at the two upwind-selectable features, packed over k.
        const v2f t1 = o1*PP[69] + o0*PP[71];
        const v2f g1 = PP[77] + PP[66]*t1
            + PP[67]*(q1*(PP[73] + PP[50]*t1) + q0*(PP[75] + PP[51]*t1));
        const v2f t2 = o1*PP[70] + o0*PP[72];
        const v2f g2 = PP[78] + PP[66]*t2
            + PP[67]*(q1*(PP[74] + PP[50]*t2) + q0*(PP[76] + PP[51]*t2));

        // ---- Selection deltas (scalars; shared feature vector for both k).
        const float d1 = (g1[0] > 0.0f) ? 0.0f : (D2[p][6][0] - Z(p,1));
        const float d2 = (g2[0] > 0.0f) ? 0.0f : (D2[p][7][0] - Z(p,2));
        const float d3 = (g1[1] > 0.0f) ? 0.0f : (D2[p][6][1] - Z(p,7));
        const float d4 = (g2[1] > 0.0f) ? 0.0f : (D2[p][7][1] - Z(p,8));

        // ---- Delta-forward: base + rank-4 correction (exact algebra).
        v2f f0 = o0 + PP[1]*d1;  f0 += PP[2]*d2;  f0 += PP[7]*d3;  f0 += PP[8]*d4;
        v2f f1 = o1 + PP[13]*d1; f1 += PP[14]*d2; f1 += PP[19]*d3; f1 += PP[20]*d4;
        const v2f pf = f0 * f1;
        const v2f dp = pf - pb;
        v2f r0 = q0 + PP[27]*d1; r0 += PP[28]*d2; r0 += PP[33]*d3; r0 += PP[34]*d4;
        r0 += PP[50]*dp;
        v2f r1 = q1 + PP[39]*d1; r1 += PP[40]*d2; r1 += PP[45]*d3; r1 += PP[46]*d4;
        r1 += PP[51]*dp;
        v2f y  = yb + PP[55]*d1; y  += PP[56]*d2; y  += PP[61]*d3; y  += PP[62]*d4;
        y  += PP[66]*dp;
        res[p] = y + PP[67]*(r0*r1);
    }

    // ---- Write: planar (final) or interleaved (intermediate).
    if (mode & M_OUTP) {
        #pragma unroll
        for (int p = 0; p < 3; ++p) {
            uout[o0i + p]         = bb0[p] + alpha * res[p][0];
            uout[o0i + PLANE + p] = bb1[p] + alpha * res[p][1];
        }
    } else {
        v2f* uo = (v2f*)uout;
        #pragma unroll
        for (int p = 0; p < 3; ++p) {
            v2f w;
            w[0] = bb0[p] + alpha * res[p][0];
            w[1] = bb1[p] + alpha * res[p][1];
            uo[si + p] = w;
        }
    }
}

extern "C" void kernel_launch(void* const* d_in, const int* in_sizes, int n_in,
                              void* d_out, int out_size, void* d_ws, size_t ws_size,
                              hipStream_t stream)
{
    const float* init = (const float*)d_in[0];
    const float* kern = (const float*)d_in[1];
    const float* pw0  = (const float*)d_in[2];
    const float* pb0  = (const float*)d_in[3];
    const float* pw1  = (const float*)d_in[4];
    const float* pb1  = (const float*)d_in[5];
    const float* pwf  = (const float*)d_in[6];
    const float* pbf  = (const float*)d_in[7];
    float* out = (float*)d_out;
    float* ws  = (float*)d_ws;

    float* bufA = ws + 512;            // NELEM floats, interleaved v2f[site]
    float* bufH = bufA + NELEM;        // NELEM floats, interleaved v2f[site]

    prep_kernel<<<dim3(1), dim3(320), 0, stream>>>(kern, pw0, pb0, pw1, pb1, pwf, pbf, ws);

    const dim3 grid(WW/TILEX, HH/TILEY, BATCH);   // (2, 24, 16) = 768 blocks
    const dim3 block(256);
    const float DTF = 0.2f, DTH = 0.1f;

    // T=1 -> 5 RK2 (midpoint) steps, 2 RHS evals each (sequential dependency).
    rhs_kernel<<<grid, block, 0, stream>>>(init, init, bufH, ws, DTH, M_INP|M_BLDS);
    rhs_kernel<<<grid, block, 0, stream>>>(bufH, init, bufA, ws, DTF, M_BPLN);
    for (int s = 0; s < 3; ++s) {
        rhs_kernel<<<grid, block, 0, stream>>>(bufA, bufA, bufH, ws, DTH, M_BLDS);
        rhs_kernel<<<grid, block, 0, stream>>>(bufH, bufA, bufA, ws, DTF, 0);
    }
    rhs_kernel<<<grid, block, 0, stream>>>(bufA, bufA, bufH, ws, DTH, M_BLDS);
    rhs_kernel<<<grid, block, 0, stream>>>(bufH, bufA, out,  ws, DTF, M_OUTP);
}

// Round 12
// 184.526 us; speedup vs baseline: 1.3119x; 1.0248x over previous
//
#include <hip/hip_runtime.h>

typedef float v2f __attribute__((ext_vector_type(2)));
typedef __attribute__((address_space(3))) char  lds_char;
typedef __attribute__((address_space(3))) void  lds_void;
typedef __attribute__((address_space(1))) const void glb_void;

#define HH 192
#define WW 192
#define BATCH 16
#define PLANE (HH*WW)              /* 36864 */
#define NELEM (BATCH*2*PLANE)      /* 1179648 */

// Tile: 96 px wide x 8 rows, 256 threads, 3 px per thread. Halo 2 each side.
// Grid = (2,24,16) = 768 blocks = 3 blocks/CU, 12 waves/CU -- the measured
// sharp optimum (R5). R7 (more blocks), R8 (fusion), R9 (6 waves) all lost.
#define TILEX 96
#define TILEY 8
#define SW 100  /* TILEX + 4 */
#define SH2 12  /* TILEY + 4 */
#define NPAIR 600   /* 12 rows x 50 site-pairs; both channels per site */

// Mode bits (wave-uniform): 1 = uin planar (init); 2 = base from staged LDS
// center (ubase==uin); 4 = base planar (init); 8 = uout planar (final out).
// Otherwise the pointer is a channel-interleaved v2f[site] buffer.
#define M_INP  1
#define M_BLDS 2
#define M_BPLN 4
#define M_OUTP 8

// Workspace: [0..200) K8T conv weights (tap-major [25][8]);
// [256..414) PP packed poly weight PAIRS as v2f {k=0, k=1};
// bufA at ws+512, bufH after (both stored channel-INTERLEAVED v2f[site]).
//
// PP index map (v2f units):
//  0..11  W0a[i]={pw0[i],pw0[24+i]}      12..23 W0b[i]={pw0[12+i],pw0[36+i]}
//  24 B0a={pb0[0],pb0[2]}  25 B0b={pb0[1],pb0[3]}
//  26..37 W1a[i]={pw1[i],pw1[26+i]}      38..49 W1b[i]={pw1[13+i],pw1[39+i]}
//  50 W112={pw1[12],pw1[38]}  51 W125={pw1[25],pw1[51]}
//  52 B1a={pb1[0],pb1[2]}  53 B1b={pb1[1],pb1[3]}
//  54..67 WF[i]={pwf[i],pwf[14+i]}  (66=WF12, 67=WF13)
//  68 BF={pbf[0],pbf[1]}
//  69,70 GW0a; 71,72 GW0b; 73,74 GW1a; 75,76 GW1b; 77,78 GWF
__global__ void prep_kernel(const float* __restrict__ kern,
                            const float* __restrict__ pw0, const float* __restrict__ pb0,
                            const float* __restrict__ pw1, const float* __restrict__ pb1,
                            const float* __restrict__ pwf, const float* __restrict__ pbf,
                            float* __restrict__ ws)
{
    int t = blockIdx.x * blockDim.x + threadIdx.x;
    if (t < 200) {
        const float inv  = 1.0f / 0.0327249f;
        const float inv2 = inv * inv;
        const float sc[6] = {1.0f, inv, inv, inv2, inv2, inv2};
        int o = t / 8, j = t % 8, dy = o / 5, dx = o % 5;
        float v;
        if (j < 6)       v =  kern[j*25 + dy*5 + dx] * sc[j];
        else if (j == 6) v = -kern[1*25 + dy*5 + (4-dx)] * sc[1];
        else             v = -kern[2*25 + (4-dy)*5 + dx] * sc[2];
        ws[o*8 + j] = v;
    } else if (t < 279) {
        int p = t - 200;
        int arr, a, b;
        if (p < 12)       { arr=0; a=p;      b=24+p; }
        else if (p < 24)  { int i=p-12; arr=0; a=12+i; b=36+i; }
        else if (p == 24) { arr=1; a=0; b=2; }
        else if (p == 25) { arr=1; a=1; b=3; }
        else if (p < 38)  { int i=p-26; arr=2; a=i;    b=26+i; }
        else if (p < 50)  { int i=p-38; arr=2; a=13+i; b=39+i; }
        else if (p == 50) { arr=2; a=12; b=38; }
        else if (p == 51) { arr=2; a=25; b=51; }
        else if (p == 52) { arr=3; a=0; b=2; }
        else if (p == 53) { arr=3; a=1; b=3; }
        else if (p < 68)  { int i=p-54; arr=4; a=i; b=14+i; }
        else if (p == 68) { arr=5; a=0; b=1; }
        else {
            const signed char   A0[10] = {1,2,13,14,1,2,14,15,1,2};
            const signed char   A1[10] = {31,32,43,44,33,34,46,47,21,22};
            const unsigned char AR[10] = {0,0,0,0,2,2,2,2,4,4};
            int i = p - 69; arr = AR[i]; a = A0[i]; b = A1[i];
        }
        const float* bases[6] = {pw0, pb0, pw1, pb1, pwf, pbf};
        v2f v; v[0] = bases[arr][a]; v[1] = bases[arr][b];
        ((v2f*)(ws + 256))[p] = v;
    }
}

// One RHS eval fused with axpy: uout = ubase + alpha * rhs(uin).
// PACKED-FP32 (v_pk_fma_f32) + DELTA-FORWARD poly (verified R10) +
// interleaved buffers / early base loads (verified R11). This round: staging
// for interleaved inputs uses __builtin_amdgcn_global_load_lds width=16
// (direct HBM/L2 -> LDS, no VGPR round-trip, no ds_write; barrier waits vmcnt
// only). LDS layout is exactly the required wave-uniform base + lane*16:
// pair i <-> LDS byte i*16 (50 pairs x 16B = one 100-v2f row, no padding).
// Arithmetic identical to R11 (bit-exact).
__global__ __launch_bounds__(256, 3) void rhs_kernel(
    const float* __restrict__ uin,
    const float* __restrict__ ubase,
    float* __restrict__ uout,
    const float* __restrict__ ws,
    float alpha, int mode)
{
    const float* K8T = ws;
    const v2f* PP = (const v2f*)(ws + 256);

    __shared__ __align__(16) v2f sh[SH2][SW];
    const int b   = blockIdx.z;
    const int ty0 = blockIdx.y * TILEY;
    const int tx0 = blockIdx.x * TILEX;
    const int tid = threadIdx.x;
    const size_t bo = (size_t)b * 2 * PLANE;

    // ---- Staging: 600 site-pairs, 2-3 iters/thread.
    if (mode & M_INP) {
        // planar init: two float2 loads -> one 16B LDS write per pair
        const float* uin_b = uin + bo;
        for (int i = tid; i < NPAIR; i += 256) {
            const int ly  = i / 50;
            const int cp  = i - ly * 50;
            const int col = cp * 2;
            int gy = ty0 + ly - 2;  if (gy < 0) gy += HH; else if (gy >= HH) gy -= HH;
            int gx0 = tx0 + col - 2; if (gx0 < 0) gx0 += WW; else if (gx0 >= WW) gx0 -= WW;
            const int gi = gy*WW + gx0;
            const float2 a = *(const float2*)(uin_b + gi);
            const float2 c = *(const float2*)(uin_b + PLANE + gi);
            float4 st; st.x = a.x; st.y = c.x; st.z = a.y; st.w = c.y;
            *(float4*)&sh[ly][col] = st;
        }
    } else {
        // interleaved buffer: direct global->LDS, 16B per lane. LDS dest is
        // wave-uniform base (pair wb = i - lane) + lane*16 (HW-applied).
        const v2f* uin_i = (const v2f*)uin + (size_t)b * PLANE;
        lds_char* lbase = (lds_char*)&sh[0][0];
        for (int i = tid; i < NPAIR; i += 256) {
            const int ly  = i / 50;
            const int cp  = i - ly * 50;
            const int col = cp * 2;
            int gy = ty0 + ly - 2;  if (gy < 0) gy += HH; else if (gy >= HH) gy -= HH;
            int gx0 = tx0 + col - 2; if (gx0 < 0) gx0 += WW; else if (gx0 >= WW) gx0 -= WW;
            const int wb16 = (i - (tid & 63)) * 16;   // wave-uniform
            __builtin_amdgcn_global_load_lds(
                (glb_void*)(uin_i + gy*WW + gx0),
                (lds_void*)(lbase + wb16), 16, 0, 0);
        }
    }

    const int cy = tid >> 5;            // 0..7
    const int x3 = (tid & 31) * 3;      // 0,3,..,93
    const int oy = ty0 + cy, ox = tx0 + x3;
    const size_t o0i = bo + (size_t)oy * WW + ox;              // planar index
    const size_t si  = (size_t)b * PLANE + (size_t)oy * WW + ox; // site index

    // ---- Base loads issued EARLY (before barrier) when from global.
    float bb0[3], bb1[3];
    if (!(mode & M_BLDS)) {
        if (mode & M_BPLN) {
            #pragma unroll
            for (int p = 0; p < 3; ++p) {
                bb0[p] = ubase[o0i + p];
                bb1[p] = ubase[o0i + PLANE + p];
            }
        } else {
            const v2f* ub = (const v2f*)ubase;
            #pragma unroll
            for (int p = 0; p < 3; ++p) {
                const v2f c = ub[si + p];
                bb0[p] = c[0]; bb1[p] = c[1];
            }
        }
    }
    __syncthreads();
    if (mode & M_BLDS) {
        #pragma unroll
        for (int p = 0; p < 3; ++p) {
            const v2f c = sh[cy+2][x3+2+p];
            bb0[p] = c[0]; bb1[p] = c[1];
        }
    }

    // ---- Conv: D2[px][j] = v2f over channels. dy loop rolled (code size).
    v2f D2[3][8];
    #pragma unroll
    for (int p = 0; p < 3; ++p)
        #pragma unroll
        for (int j = 0; j < 8; ++j)
            D2[p][j] = (v2f){0.0f, 0.0f};

    #pragma unroll 1
    for (int dy = 0; dy < 5; ++dy) {
        v2f row[7];
        #pragma unroll
        for (int dx = 0; dx < 7; ++dx)
            row[dx] = sh[cy + dy][x3 + dx];
        const float* Kt = K8T + dy * 40;   // 5 taps x 8 weights
        #pragma unroll
        for (int dx = 0; dx < 5; ++dx) {
            #pragma unroll
            for (int j = 0; j < 8; ++j) {
                const float w = Kt[dx*8 + j];
                D2[0][j] += row[dx]   * w;   // v_pk_fma_f32: both channels
                D2[1][j] += row[dx+1] * w;
                D2[2][j] += row[dx+2] * w;
            }
        }
    }

    // Feature i of pixel p: channel = i/6, map = i%6.
#define Z(p,i) (D2[p][(i)%6][(i)/6])

    v2f res[3];   // {k=0, k=1} per pixel
    #pragma unroll
    for (int p = 0; p < 3; ++p) {
        // ---- Base pass, packed over k; also accumulates yb (final linear).
        v2f o0 = PP[24], o1 = PP[25];
        #pragma unroll
        for (int i = 0; i < 12; ++i) {
            const float zv = Z(p, i);
            o0 += PP[i]    * zv;
            o1 += PP[12+i] * zv;
        }
        const v2f pb = o0 * o1;
        v2f q0 = PP[52] + PP[50]*pb;
        v2f q1 = PP[53] + PP[51]*pb;
        v2f yb = PP[68] + PP[66]*pb;
        #pragma unroll
        for (int i = 0; i < 12; ++i) {
            const float zv = Z(p, i);
            q0 += PP[26+i] * zv;
            q1 += PP[38+i] * zv;
            yb += PP[54+i] * zv;
        }

        // ---- Gradients at the two upwind-selectable features, packed over k.
        const v2f t1 = o1*PP[69] + o0*PP[71];
        const v2f g1 = PP[77] + PP[66]*t1
            + PP[67]*(q1*(PP[73] + PP[50]*t1) + q0*(PP[75] + PP[51]*t1));
        const v2f t2 = o1*PP[70] + o0*PP[72];
        const v2f g2 = PP[78] + PP[66]*t2
            + PP[67]*(q1*(PP[74] + PP[50]*t2) + q0*(PP[76] + PP[51]*t2));

        // ---- Selection deltas (scalars; shared feature vector for both k).
        const float d1 = (g1[0] > 0.0f) ? 0.0f : (D2[p][6][0] - Z(p,1));
        const float d2 = (g2[0] > 0.0f) ? 0.0f : (D2[p][7][0] - Z(p,2));
        const float d3 = (g1[1] > 0.0f) ? 0.0f : (D2[p][6][1] - Z(p,7));
        const float d4 = (g2[1] > 0.0f) ? 0.0f : (D2[p][7][1] - Z(p,8));

        // ---- Delta-forward: base + rank-4 correction (exact algebra).
        v2f f0 = o0 + PP[1]*d1;  f0 += PP[2]*d2;  f0 += PP[7]*d3;  f0 += PP[8]*d4;
        v2f f1 = o1 + PP[13]*d1; f1 += PP[14]*d2; f1 += PP[19]*d3; f1 += PP[20]*d4;
        const v2f pf = f0 * f1;
        const v2f dp = pf - pb;
        v2f r0 = q0 + PP[27]*d1; r0 += PP[28]*d2; r0 += PP[33]*d3; r0 += PP[34]*d4;
        r0 += PP[50]*dp;
        v2f r1 = q1 + PP[39]*d1; r1 += PP[40]*d2; r1 += PP[45]*d3; r1 += PP[46]*d4;
        r1 += PP[51]*dp;
        v2f y  = yb + PP[55]*d1; y  += PP[56]*d2; y  += PP[61]*d3; y  += PP[62]*d4;
        y  += PP[66]*dp;
        res[p] = y + PP[67]*(r0*r1);
    }

    // ---- Write: planar (final) or interleaved (intermediate).
    if (mode & M_OUTP) {
        #pragma unroll
        for (int p = 0; p < 3; ++p) {
            uout[o0i + p]         = bb0[p] + alpha * res[p][0];
            uout[o0i + PLANE + p] = bb1[p] + alpha * res[p][1];
        }
    } else {
        v2f* uo = (v2f*)uout;
        #pragma unroll
        for (int p = 0; p < 3; ++p) {
            v2f w;
            w[0] = bb0[p] + alpha * res[p][0];
            w[1] = bb1[p] + alpha * res[p][1];
            uo[si + p] = w;
        }
    }
}

extern "C" void kernel_launch(void* const* d_in, const int* in_sizes, int n_in,
                              void* d_out, int out_size, void* d_ws, size_t ws_size,
                              hipStream_t stream)
{
    const float* init = (const float*)d_in[0];
    const float* kern = (const float*)d_in[1];
    const float* pw0  = (const float*)d_in[2];
    const float* pb0  = (const float*)d_in[3];
    const float* pw1  = (const float*)d_in[4];
    const float* pb1  = (const float*)d_in[5];
    const float* pwf  = (const float*)d_in[6];
    const float* pbf  = (const float*)d_in[7];
    float* out = (float*)d_out;
    float* ws  = (float*)d_ws;

    float* bufA = ws + 512;            // NELEM floats, interleaved v2f[site]
    float* bufH = bufA + NELEM;        // NELEM floats, interleaved v2f[site]

    prep_kernel<<<dim3(1), dim3(320), 0, stream>>>(kern, pw0, pb0, pw1, pb1, pwf, pbf, ws);

    const dim3 grid(WW/TILEX, HH/TILEY, BATCH);   // (2, 24, 16) = 768 blocks
    const dim3 block(256);
    const float DTF = 0.2f, DTH = 0.1f;

    // T=1 -> 5 RK2 (midpoint) steps, 2 RHS evals each (sequential dependency).
    rhs_kernel<<<grid, block, 0, stream>>>(init, init, bufH, ws, DTH, M_INP|M_BLDS);
    rhs_kernel<<<grid, block, 0, stream>>>(bufH, init, bufA, ws, DTF, M_BPLN);
    for (int s = 0; s < 3; ++s) {
        rhs_kernel<<<grid, block, 0, stream>>>(bufA, bufA, bufH, ws, DTH, M_BLDS);
        rhs_kernel<<<grid, block, 0, stream>>>(bufH, bufA, bufA, ws, DTF, 0);
    }
    rhs_kernel<<<grid, block, 0, stream>>>(bufA, bufA, bufH, ws, DTH, M_BLDS);
    rhs_kernel<<<grid, block, 0, stream>>>(bufH, bufA, out,  ws, DTF, M_OUTP);
}

// Round 13
// 184.023 us; speedup vs baseline: 1.3154x; 1.0027x over previous
//
#include <hip/hip_runtime.h>

typedef float v2f __attribute__((ext_vector_type(2)));
typedef __attribute__((address_space(3))) char  lds_char;
typedef __attribute__((address_space(3))) void  lds_void;
typedef __attribute__((address_space(1))) const void glb_void;

#define HH 192
#define WW 192
#define BATCH 16
#define PLANE (HH*WW)              /* 36864 */
#define NELEM (BATCH*2*PLANE)      /* 1179648 */

// Tile: 96 px wide x 8 rows, 256 threads, 3 px per thread. Halo 2 each side.
// Grid = (2,24,16) = 768 blocks = 3 blocks/CU, 12 waves/CU -- the measured
// sharp optimum (R5). R7 (more blocks), R8 (fusion), R9 (6 waves) all lost.
#define TILEX 96
#define TILEY 8
#define SW 100  /* TILEX + 4 */
#define SH2 12  /* TILEY + 4 */
#define NPAIR 600   /* 12 rows x 50 site-pairs; both channels per site */

// Mode bits (wave-uniform): 1 = uin planar (init); 4 = base planar (init);
// 8 = uout planar (final out). Otherwise channel-interleaved v2f[site].
// Base is ALWAYS loaded early from global (pre-barrier; hides under staging
// wait) -- when ubase==uin this reads the same memory the staging reads,
// bit-identical to the old LDS-center path.
#define M_INP  1
#define M_BPLN 4
#define M_OUTP 8

// Workspace: [0..200) K8T conv weights (tap-major [25][8]);
// [256..414) PP packed poly weight PAIRS as v2f {k=0, k=1};
// bufA at ws+512, bufH after (both stored channel-INTERLEAVED v2f[site]).
//
// PP index map (v2f units):
//  0..11  W0a[i]={pw0[i],pw0[24+i]}      12..23 W0b[i]={pw0[12+i],pw0[36+i]}
//  24 B0a={pb0[0],pb0[2]}  25 B0b={pb0[1],pb0[3]}
//  26..37 W1a[i]={pw1[i],pw1[26+i]}      38..49 W1b[i]={pw1[13+i],pw1[39+i]}
//  50 W112={pw1[12],pw1[38]}  51 W125={pw1[25],pw1[51]}
//  52 B1a={pb1[0],pb1[2]}  53 B1b={pb1[1],pb1[3]}
//  54..67 WF[i]={pwf[i],pwf[14+i]}  (66=WF12, 67=WF13)
//  68 BF={pbf[0],pbf[1]}
//  69,70 GW0a; 71,72 GW0b; 73,74 GW1a; 75,76 GW1b; 77,78 GWF
__global__ void prep_kernel(const float* __restrict__ kern,
                            const float* __restrict__ pw0, const float* __restrict__ pb0,
                            const float* __restrict__ pw1, const float* __restrict__ pb1,
                            const float* __restrict__ pwf, const float* __restrict__ pbf,
                            float* __restrict__ ws)
{
    int t = blockIdx.x * blockDim.x + threadIdx.x;
    if (t < 200) {
        const float inv  = 1.0f / 0.0327249f;
        const float inv2 = inv * inv;
        const float sc[6] = {1.0f, inv, inv, inv2, inv2, inv2};
        int o = t / 8, j = t % 8, dy = o / 5, dx = o % 5;
        float v;
        if (j < 6)       v =  kern[j*25 + dy*5 + dx] * sc[j];
        else if (j == 6) v = -kern[1*25 + dy*5 + (4-dx)] * sc[1];
        else             v = -kern[2*25 + (4-dy)*5 + dx] * sc[2];
        ws[o*8 + j] = v;
    } else if (t < 279) {
        int p = t - 200;
        int arr, a, b;
        if (p < 12)       { arr=0; a=p;      b=24+p; }
        else if (p < 24)  { int i=p-12; arr=0; a=12+i; b=36+i; }
        else if (p == 24) { arr=1; a=0; b=2; }
        else if (p == 25) { arr=1; a=1; b=3; }
        else if (p < 38)  { int i=p-26; arr=2; a=i;    b=26+i; }
        else if (p < 50)  { int i=p-38; arr=2; a=13+i; b=39+i; }
        else if (p == 50) { arr=2; a=12; b=38; }
        else if (p == 51) { arr=2; a=25; b=51; }
        else if (p == 52) { arr=3; a=0; b=2; }
        else if (p == 53) { arr=3; a=1; b=3; }
        else if (p < 68)  { int i=p-54; arr=4; a=i; b=14+i; }
        else if (p == 68) { arr=5; a=0; b=1; }
        else {
            const signed char   A0[10] = {1,2,13,14,1,2,14,15,1,2};
            const signed char   A1[10] = {31,32,43,44,33,34,46,47,21,22};
            const unsigned char AR[10] = {0,0,0,0,2,2,2,2,4,4};
            int i = p - 69; arr = AR[i]; a = A0[i]; b = A1[i];
        }
        const float* bases[6] = {pw0, pb0, pw1, pb1, pwf, pbf};
        v2f v; v[0] = bases[arr][a]; v[1] = bases[arr][b];
        ((v2f*)(ws + 256))[p] = v;
    }
}

// One RHS eval fused with axpy: uout = ubase + alpha * rhs(uin).
// PACKED-FP32 (v_pk_fma_f32) + DELTA-FORWARD poly (R10) + interleaved
// buffers (R11) + global_load_lds width=16 staging (R12). This round:
// staging loop explicitly unrolled (3 chunks, back-to-back issue) and base
// loads always early-from-global (pre-barrier, fully hidden; bit-identical
// values). Arithmetic identical to R12.
__global__ __launch_bounds__(256, 3) void rhs_kernel(
    const float* __restrict__ uin,
    const float* __restrict__ ubase,
    float* __restrict__ uout,
    const float* __restrict__ ws,
    float alpha, int mode)
{
    const float* K8T = ws;
    const v2f* PP = (const v2f*)(ws + 256);

    __shared__ __align__(16) v2f sh[SH2][SW];
    const int b   = blockIdx.z;
    const int ty0 = blockIdx.y * TILEY;
    const int tx0 = blockIdx.x * TILEX;
    const int tid = threadIdx.x;
    const size_t bo = (size_t)b * 2 * PLANE;

    // ---- Staging: 600 site-pairs, explicitly unrolled (i = tid, +256, +512).
    if (mode & M_INP) {
        // planar init: two float2 loads -> one 16B LDS write per pair
        const float* uin_b = uin + bo;
        #pragma unroll
        for (int k = 0; k < 3; ++k) {
            const int i = tid + 256*k;
            if (k == 2 && i >= NPAIR) break;
            const int ly  = i / 50;
            const int cp  = i - ly * 50;
            const int col = cp * 2;
            int gy = ty0 + ly - 2;  if (gy < 0) gy += HH; else if (gy >= HH) gy -= HH;
            int gx0 = tx0 + col - 2; if (gx0 < 0) gx0 += WW; else if (gx0 >= WW) gx0 -= WW;
            const int gi = gy*WW + gx0;
            const float2 a = *(const float2*)(uin_b + gi);
            const float2 c = *(const float2*)(uin_b + PLANE + gi);
            float4 st; st.x = a.x; st.y = c.x; st.z = a.y; st.w = c.y;
            *(float4*)&sh[ly][col] = st;
        }
    } else {
        // interleaved buffer: direct global->LDS, 16B per lane. LDS dest is
        // wave-uniform base (pair wb = i - lane) + lane*16 (HW-applied).
        const v2f* uin_i = (const v2f*)uin + (size_t)b * PLANE;
        lds_char* lbase = (lds_char*)&sh[0][0];
        #pragma unroll
        for (int k = 0; k < 3; ++k) {
            const int i = tid + 256*k;
            if (k == 2 && i >= NPAIR) break;
            const int ly  = i / 50;
            const int cp  = i - ly * 50;
            const int col = cp * 2;
            int gy = ty0 + ly - 2;  if (gy < 0) gy += HH; else if (gy >= HH) gy -= HH;
            int gx0 = tx0 + col - 2; if (gx0 < 0) gx0 += WW; else if (gx0 >= WW) gx0 -= WW;
            const int wb16 = (i - (tid & 63)) * 16;   // wave-uniform
            __builtin_amdgcn_global_load_lds(
                (glb_void*)(uin_i + gy*WW + gx0),
                (lds_void*)(lbase + wb16), 16, 0, 0);
        }
    }

    const int cy = tid >> 5;            // 0..7
    const int x3 = (tid & 31) * 3;      // 0,3,..,93
    const int oy = ty0 + cy, ox = tx0 + x3;
    const size_t o0i = bo + (size_t)oy * WW + ox;              // planar index
    const size_t si  = (size_t)b * PLANE + (size_t)oy * WW + ox; // site index

    // ---- Base loads: ALWAYS early (pre-barrier), hidden under staging wait.
    float bb0[3], bb1[3];
    if (mode & M_BPLN) {
        #pragma unroll
        for (int p = 0; p < 3; ++p) {
            bb0[p] = ubase[o0i + p];
            bb1[p] = ubase[o0i + PLANE + p];
        }
    } else {
        const v2f* ub = (const v2f*)ubase;
        #pragma unroll
        for (int p = 0; p < 3; ++p) {
            const v2f c = ub[si + p];
            bb0[p] = c[0]; bb1[p] = c[1];
        }
    }
    __syncthreads();

    // ---- Conv: D2[px][j] = v2f over channels. dy loop rolled (code size).
    v2f D2[3][8];
    #pragma unroll
    for (int p = 0; p < 3; ++p)
        #pragma unroll
        for (int j = 0; j < 8; ++j)
            D2[p][j] = (v2f){0.0f, 0.0f};

    #pragma unroll 1
    for (int dy = 0; dy < 5; ++dy) {
        v2f row[7];
        #pragma unroll
        for (int dx = 0; dx < 7; ++dx)
            row[dx] = sh[cy + dy][x3 + dx];
        const float* Kt = K8T + dy * 40;   // 5 taps x 8 weights
        #pragma unroll
        for (int dx = 0; dx < 5; ++dx) {
            #pragma unroll
            for (int j = 0; j < 8; ++j) {
                const float w = Kt[dx*8 + j];
                D2[0][j] += row[dx]   * w;   // v_pk_fma_f32: both channels
                D2[1][j] += row[dx+1] * w;
                D2[2][j] += row[dx+2] * w;
            }
        }
    }

    // Feature i of pixel p: channel = i/6, map = i%6.
#define Z(p,i) (D2[p][(i)%6][(i)/6])

    v2f res[3];   // {k=0, k=1} per pixel
    #pragma unroll
    for (int p = 0; p < 3; ++p) {
        // ---- Base pass, packed over k; also accumulates yb (final linear).
        v2f o0 = PP[24], o1 = PP[25];
        #pragma unroll
        for (int i = 0; i < 12; ++i) {
            const float zv = Z(p, i);
            o0 += PP[i]    * zv;
            o1 += PP[12+i] * zv;
        }
        const v2f pb = o0 * o1;
        v2f q0 = PP[52] + PP[50]*pb;
        v2f q1 = PP[53] + PP[51]*pb;
        v2f yb = PP[68] + PP[66]*pb;
        #pragma unroll
        for (int i = 0; i < 12; ++i) {
            const float zv = Z(p, i);
            q0 += PP[26+i] * zv;
            q1 += PP[38+i] * zv;
            yb += PP[54+i] * zv;
        }

        // ---- Gradients at the two upwind-selectable features, packed over k.
        const v2f t1 = o1*PP[69] + o0*PP[71];
        const v2f g1 = PP[77] + PP[66]*t1
            + PP[67]*(q1*(PP[73] + PP[50]*t1) + q0*(PP[75] + PP[51]*t1));
        const v2f t2 = o1*PP[70] + o0*PP[72];
        const v2f g2 = PP[78] + PP[66]*t2
            + PP[67]*(q1*(PP[74] + PP[50]*t2) + q0*(PP[76] + PP[51]*t2));

        // ---- Selection deltas (scalars; shared feature vector for both k).
        const float d1 = (g1[0] > 0.0f) ? 0.0f : (D2[p][6][0] - Z(p,1));
        const float d2 = (g2[0] > 0.0f) ? 0.0f : (D2[p][7][0] - Z(p,2));
        const float d3 = (g1[1] > 0.0f) ? 0.0f : (D2[p][6][1] - Z(p,7));
        const float d4 = (g2[1] > 0.0f) ? 0.0f : (D2[p][7][1] - Z(p,8));

        // ---- Delta-forward: base + rank-4 correction (exact algebra).
        v2f f0 = o0 + PP[1]*d1;  f0 += PP[2]*d2;  f0 += PP[7]*d3;  f0 += PP[8]*d4;
        v2f f1 = o1 + PP[13]*d1; f1 += PP[14]*d2; f1 += PP[19]*d3; f1 += PP[20]*d4;
        const v2f pf = f0 * f1;
        const v2f dp = pf - pb;
        v2f r0 = q0 + PP[27]*d1; r0 += PP[28]*d2; r0 += PP[33]*d3; r0 += PP[34]*d4;
        r0 += PP[50]*dp;
        v2f r1 = q1 + PP[39]*d1; r1 += PP[40]*d2; r1 += PP[45]*d3; r1 += PP[46]*d4;
        r1 += PP[51]*dp;
        v2f y  = yb + PP[55]*d1; y  += PP[56]*d2; y  += PP[61]*d3; y  += PP[62]*d4;
        y  += PP[66]*dp;
        res[p] = y + PP[67]*(r0*r1);
    }

    // ---- Write: planar (final) or interleaved (intermediate).
    if (mode & M_OUTP) {
        #pragma unroll
        for (int p = 0; p < 3; ++p) {
            uout[o0i + p]         = bb0[p] + alpha * res[p][0];
            uout[o0i + PLANE + p] = bb1[p] + alpha * res[p][1];
        }
    } else {
        v2f* uo = (v2f*)uout;
        #pragma unroll
        for (int p = 0; p < 3; ++p) {
            v2f w;
            w[0] = bb0[p] + alpha * res[p][0];
            w[1] = bb1[p] + alpha * res[p][1];
            uo[si + p] = w;
        }
    }
}

extern "C" void kernel_launch(void* const* d_in, const int* in_sizes, int n_in,
                              void* d_out, int out_size, void* d_ws, size_t ws_size,
                              hipStream_t stream)
{
    const float* init = (const float*)d_in[0];
    const float* kern = (const float*)d_in[1];
    const float* pw0  = (const float*)d_in[2];
    const float* pb0  = (const float*)d_in[3];
    const float* pw1  = (const float*)d_in[4];
    const float* pb1  = (const float*)d_in[5];
    const float* pwf  = (const float*)d_in[6];
    const float* pbf  = (const float*)d_in[7];
    float* out = (float*)d_out;
    float* ws  = (float*)d_ws;

    float* bufA = ws + 512;            // NELEM floats, interleaved v2f[site]
    float* bufH = bufA + NELEM;        // NELEM floats, interleaved v2f[site]

    prep_kernel<<<dim3(1), dim3(320), 0, stream>>>(kern, pw0, pb0, pw1, pb1, pwf, pbf, ws);

    const dim3 grid(WW/TILEX, HH/TILEY, BATCH);   // (2, 24, 16) = 768 blocks
    const dim3 block(256);
    const float DTF = 0.2f, DTH = 0.1f;

    // T=1 -> 5 RK2 (midpoint) steps, 2 RHS evals each (sequential dependency).
    rhs_kernel<<<grid, block, 0, stream>>>(init, init, bufH, ws, DTH, M_INP|M_BPLN);
    rhs_kernel<<<grid, block, 0, stream>>>(bufH, init, bufA, ws, DTF, M_BPLN);
    for (int s = 0; s < 3; ++s) {
        rhs_kernel<<<grid, block, 0, stream>>>(bufA, bufA, bufH, ws, DTH, 0);
        rhs_kernel<<<grid, block, 0, stream>>>(bufH, bufA, bufA, ws, DTF, 0);
    }
    rhs_kernel<<<grid, block, 0, stream>>>(bufA, bufA, bufH, ws, DTH, 0);
    rhs_kernel<<<grid, block, 0, stream>>>(bufH, bufA, out,  ws, DTF, M_OUTP);
}